// Round 4
// baseline (2307.606 us; speedup 1.0000x reference)
//
#include <hip/hip_runtime.h>
#include <hip/hip_bf16.h>

#define NN 50000
#define NE 800000
#define EPSV 1e-5f

// ---------------- graph preprocessing ----------------

__global__ void k_deg(const int* __restrict__ dst, int* __restrict__ deg){
  int e = blockIdx.x*blockDim.x + threadIdx.x;
  if(e < NE) atomicAdd(&deg[dst[e]], 1);
}

__global__ void k_logdeg(const int* __restrict__ deg, float* __restrict__ logdeg,
                         float* __restrict__ dsum){
  int i = blockIdx.x*blockDim.x + threadIdx.x;
  float v = 0.f;
  if(i < NN){ v = log1pf((float)deg[i]); logdeg[i] = v; }
  __shared__ float sh[256];
  sh[threadIdx.x] = v; __syncthreads();
  for(int off=128; off>0; off>>=1){
    if(threadIdx.x < off) sh[threadIdx.x] += sh[threadIdx.x+off];
    __syncthreads();
  }
  if(threadIdx.x == 0) atomicAdd(dsum, sh[0]);
}

__global__ void k_scalers(const float* __restrict__ logdeg, const float* __restrict__ dsum,
                          float* __restrict__ amp, float* __restrict__ att){
  int i = blockIdx.x*blockDim.x + threadIdx.x;
  if(i >= NN) return;
  float delta = dsum[0] / (float)NN;
  float ld = logdeg[i];
  amp[i] = ld / delta;
  att[i] = (ld > 0.f) ? (delta / fmaxf(ld, 1e-6f)) : 1.f;
}

__global__ void k_scan(const int* __restrict__ deg, int* __restrict__ rowptr,
                       int* __restrict__ cursor){
  __shared__ int buf[1024];
  __shared__ int s_carry;
  int tid = threadIdx.x;
  if(tid == 0) s_carry = 0;
  __syncthreads();
  for(int base=0; base<NN; base+=1024){
    int i = base + tid;
    int v = (i < NN) ? deg[i] : 0;
    buf[tid] = v; __syncthreads();
    for(int off=1; off<1024; off<<=1){
      int t = (tid >= off) ? buf[tid-off] : 0;
      __syncthreads();
      buf[tid] += t;
      __syncthreads();
    }
    int c = s_carry;
    int excl = c + buf[tid] - v;
    if(i < NN){ rowptr[i] = excl; cursor[i] = excl; }
    __syncthreads();
    if(tid == 1023) s_carry = c + buf[1023];
    __syncthreads();
  }
  if(tid == 0) rowptr[NN] = s_carry;
}

__global__ void k_fill(const int* __restrict__ src, const int* __restrict__ dst,
                       int* __restrict__ cursor, int* __restrict__ colidx){
  int e = blockIdx.x*blockDim.x + threadIdx.x;
  if(e < NE){
    int pos = atomicAdd(&cursor[dst[e]], 1);
    colidx[pos] = src[e];
  }
}

// ---------------- chunked per-node aggregation ----------------
// Processes feature columns [j0, j0+64) of h[N,d] -> aggsC[N][4][64] fp32
// (mean | min | max | std), reused across chunks.

__global__ void k_agg_chunk(const float* __restrict__ h, int d, int j0,
                            const int* __restrict__ rowptr, const int* __restrict__ colidx,
                            float* __restrict__ aggsC){
  int n = blockIdx.x;
  int j = threadIdx.x;   // 0..63
  int beg = rowptr[n], end = rowptr[n+1];
  float s = 0.f, ss = 0.f, mn = INFINITY, mx = -INFINITY;
  for(int e = beg; e < end; e++){
    int sidx = colidx[e];
    float v = h[(size_t)sidx*d + j0 + j];
    s += v; ss += v*v;
    mn = fminf(mn, v); mx = fmaxf(mx, v);
  }
  float cnt  = (end > beg) ? (float)(end - beg) : 1.f;
  float mean = s / cnt;
  float msq  = ss / cnt;
  float sd   = sqrtf(fmaxf(msq - mean*mean, 0.f) + EPSV);
  if(end <= beg){ mn = 0.f; mx = 0.f; }
  size_t base = (size_t)n * 256;
  aggsC[base + j]       = mean;
  aggsC[base + 64 + j]  = mn;
  aggsC[base + 128 + j] = mx;
  aggsC[base + 192 + j] = sd;
}

// ---------------- fused chunked layer GEMM ----------------
// Per chunk c (features [j0,j0+64) of d):
//   hB[m,:] (+)= hA[m,j0:j0+64] @ W[j0:j0+64]
//             + sum_q aggsC[m,q,:] @ ( W[(1+q)d+j0 ...] + amp[m]*W[(5+q)d+j0 ...] + att[m]*W[(9+q)d+j0 ...] )
// init chunk adds bias; output stays pre-ReLU fp32.

#define BM 64
#define BN 64
#define BK 16

__global__ __launch_bounds__(256) void k_gemm_chunk(
    const float* __restrict__ hA, int d, int j0,
    const float* __restrict__ aggsC,
    const float* __restrict__ amp, const float* __restrict__ att,
    const float* __restrict__ W, int o,
    const float* __restrict__ bias,
    float* __restrict__ hB, int init)
{
  __shared__ float As[BK][BM+4];
  __shared__ float B0[BK][BN+4];
  __shared__ float B1[BK][BN+4];
  __shared__ float B2[BK][BN+4];
  int tid = threadIdx.x;
  int m0 = blockIdx.y * BM;
  int c0 = blockIdx.x * BN;
  int tx = tid & 15, ty = tid >> 4;

  int arow = tid >> 2;          // 0..63
  int akq  = (tid & 3) << 2;    // 0,4,8,12
  int am = m0 + arow;
  bool avalid = am < NN;

  int brow = tid >> 4;          // 0..15
  int bcq  = (tid & 15) << 2;   // 0..60

  float accA[4][4] = {};
  float accP[4][4] = {};
  float accT[4][4] = {};

  // ---- phase 1: hA[:, j0:j0+64] @ W[j0:j0+64] ----
  const float* Ap = hA + (size_t)am * d + j0;
  for(int k0 = 0; k0 < 64; k0 += BK){
    float4 av = avalid ? *(const float4*)(Ap + k0 + akq) : make_float4(0,0,0,0);
    As[akq+0][arow] = av.x;
    As[akq+1][arow] = av.y;
    As[akq+2][arow] = av.z;
    As[akq+3][arow] = av.w;
    float4 wv = *(const float4*)(W + (size_t)(j0 + k0 + brow)*o + c0 + bcq);
    *(float4*)(&B0[brow][bcq]) = wv;
    __syncthreads();
    #pragma unroll
    for(int kk = 0; kk < BK; kk++){
      float4 a = *(const float4*)(&As[kk][ty<<2]);
      float4 b = *(const float4*)(&B0[kk][tx<<2]);
      accA[0][0] += a.x*b.x; accA[0][1] += a.x*b.y; accA[0][2] += a.x*b.z; accA[0][3] += a.x*b.w;
      accA[1][0] += a.y*b.x; accA[1][1] += a.y*b.y; accA[1][2] += a.y*b.z; accA[1][3] += a.y*b.w;
      accA[2][0] += a.z*b.x; accA[2][1] += a.z*b.y; accA[2][2] += a.z*b.z; accA[2][3] += a.z*b.w;
      accA[3][0] += a.w*b.x; accA[3][1] += a.w*b.y; accA[3][2] += a.w*b.z; accA[3][3] += a.w*b.w;
    }
    __syncthreads();
  }

  // ---- phase 2: aggsC[N,256] vs W rows (1+q)d / (5+q)d / (9+q)d + j0 ----
  const float* Gp = aggsC + (size_t)am * 256;
  for(int k0 = 0; k0 < 256; k0 += BK){
    float4 av = avalid ? *(const float4*)(Gp + k0 + akq) : make_float4(0,0,0,0);
    As[akq+0][arow] = av.x;
    As[akq+1][arow] = av.y;
    As[akq+2][arow] = av.z;
    As[akq+3][arow] = av.w;
    int q = k0 >> 6;            // aggregator index (BK=16 never straddles q)
    int r = (k0 & 63) + brow;   // row within aggregator chunk
    size_t wbase = (size_t)(j0 + r);
    float4 w0 = *(const float4*)(W + ((size_t)(1+q)*d + wbase)*o + c0 + bcq);
    float4 w1 = *(const float4*)(W + ((size_t)(5+q)*d + wbase)*o + c0 + bcq);
    float4 w2 = *(const float4*)(W + ((size_t)(9+q)*d + wbase)*o + c0 + bcq);
    *(float4*)(&B0[brow][bcq]) = w0;
    *(float4*)(&B1[brow][bcq]) = w1;
    *(float4*)(&B2[brow][bcq]) = w2;
    __syncthreads();
    #pragma unroll
    for(int kk = 0; kk < BK; kk++){
      float4 a  = *(const float4*)(&As[kk][ty<<2]);
      float4 b0 = *(const float4*)(&B0[kk][tx<<2]);
      float4 b1 = *(const float4*)(&B1[kk][tx<<2]);
      float4 b2 = *(const float4*)(&B2[kk][tx<<2]);
      accA[0][0] += a.x*b0.x; accA[0][1] += a.x*b0.y; accA[0][2] += a.x*b0.z; accA[0][3] += a.x*b0.w;
      accA[1][0] += a.y*b0.x; accA[1][1] += a.y*b0.y; accA[1][2] += a.y*b0.z; accA[1][3] += a.y*b0.w;
      accA[2][0] += a.z*b0.x; accA[2][1] += a.z*b0.y; accA[2][2] += a.z*b0.z; accA[2][3] += a.z*b0.w;
      accA[3][0] += a.w*b0.x; accA[3][1] += a.w*b0.y; accA[3][2] += a.w*b0.z; accA[3][3] += a.w*b0.w;
      accP[0][0] += a.x*b1.x; accP[0][1] += a.x*b1.y; accP[0][2] += a.x*b1.z; accP[0][3] += a.x*b1.w;
      accP[1][0] += a.y*b1.x; accP[1][1] += a.y*b1.y; accP[1][2] += a.y*b1.z; accP[1][3] += a.y*b1.w;
      accP[2][0] += a.z*b1.x; accP[2][1] += a.z*b1.y; accP[2][2] += a.z*b1.z; accP[2][3] += a.z*b1.w;
      accP[3][0] += a.w*b1.x; accP[3][1] += a.w*b1.y; accP[3][2] += a.w*b1.z; accP[3][3] += a.w*b1.w;
      accT[0][0] += a.x*b2.x; accT[0][1] += a.x*b2.y; accT[0][2] += a.x*b2.z; accT[0][3] += a.x*b2.w;
      accT[1][0] += a.y*b2.x; accT[1][1] += a.y*b2.y; accT[1][2] += a.y*b2.z; accT[1][3] += a.y*b2.w;
      accT[2][0] += a.z*b2.x; accT[2][1] += a.z*b2.y; accT[2][2] += a.z*b2.z; accT[2][3] += a.z*b2.w;
      accT[3][0] += a.w*b2.x; accT[3][1] += a.w*b2.y; accT[3][2] += a.w*b2.z; accT[3][3] += a.w*b2.w;
    }
    __syncthreads();
  }

  #pragma unroll
  for(int i = 0; i < 4; i++){
    int m = m0 + (ty<<2) + i;
    if(m >= NN) continue;
    float ampv = amp[m], attv = att[m];
    float* cp = hB + (size_t)m*o + c0 + (tx<<2);
    float4 base;
    if(init) base = *(const float4*)(bias + c0 + (tx<<2));
    else     base = *(const float4*)cp;
    float4 ov;
    ov.x = base.x + accA[i][0] + ampv*accP[i][0] + attv*accT[i][0];
    ov.y = base.y + accA[i][1] + ampv*accP[i][1] + attv*accT[i][1];
    ov.z = base.z + accA[i][2] + ampv*accP[i][2] + attv*accT[i][2];
    ov.w = base.w + accA[i][3] + ampv*accP[i][3] + attv*accT[i][3];
    *(float4*)cp = ov;
  }
}

// ---------------- ReLU + BatchNorm ----------------

__global__ __launch_bounds__(256) void k_bn_stats(const float* __restrict__ H, int dout,
                                                  float* __restrict__ colsum, float* __restrict__ colss){
  int tid = threadIdx.x;
  int gid = blockIdx.x*256 + tid;
  int stride = gridDim.x*256;   // multiple of dout
  int total = NN * dout;
  float s = 0.f, ss = 0.f;
  for(int i = gid; i < total; i += stride){
    float v = fmaxf(H[i], 0.f);
    s += v; ss += v*v;
  }
  __shared__ float shs[256], shss[256];
  shs[tid] = s; shss[tid] = ss;
  __syncthreads();
  if(tid < dout){
    float ts = 0.f, tss = 0.f;
    for(int i = tid; i < 256; i += dout){ ts += shs[i]; tss += shss[i]; }
    atomicAdd(&colsum[tid], ts);
    atomicAdd(&colss[tid], tss);
  }
}

__global__ void k_bn_apply(const float* __restrict__ H, int dout,
                           const float* __restrict__ colsum, const float* __restrict__ colss,
                           const float* __restrict__ gamma, const float* __restrict__ beta,
                           float* __restrict__ out){
  int i = blockIdx.x*blockDim.x + threadIdx.x;
  int total = NN * dout;
  if(i >= total) return;
  int c = i & (dout - 1);   // dout is a power of two
  float mean = colsum[c] / (float)NN;
  float var  = colss[c] / (float)NN - mean*mean;
  float inv  = rsqrtf(fmaxf(var, 0.f) + EPSV);
  float v = fmaxf(H[i], 0.f);
  out[i] = (v - mean) * inv * gamma[c] + beta[c];
}

// ---------------- classifier (fp32 out) ----------------

__global__ __launch_bounds__(256) void k_cls(const float* __restrict__ h,
    const float* __restrict__ Wc, const float* __restrict__ bc,
    float* __restrict__ out){
  __shared__ float w[640];
  __shared__ float bb[16];
  int tid = threadIdx.x;
  for(int i = tid; i < 640; i += 256) w[i] = Wc[i];
  if(tid < 10) bb[tid] = bc[tid];
  __syncthreads();
  int idx = blockIdx.x*256 + tid;
  int n = idx >> 4;
  int c = idx & 15;
  if(n < NN && c < 10){
    float acc = bb[c];
    const float* hp = h + (size_t)n*64;
    #pragma unroll
    for(int k = 0; k < 64; k++) acc += hp[k] * w[k*10 + c];
    out[(size_t)n*10 + c] = acc;
  }
}

// ---------------- launch ----------------

extern "C" void kernel_launch(void* const* d_in, const int* in_sizes, int n_in,
                              void* d_out, int out_size, void* d_ws, size_t ws_size,
                              hipStream_t stream){
  const float* x = (const float*)d_in[0];
  const int* edge = (const int*)d_in[1];
  const int* esrc = edge;
  const int* edst = edge + NE;
  const float* W[4]  = {(const float*)d_in[2],  (const float*)d_in[6],
                        (const float*)d_in[10], (const float*)d_in[14]};
  const float* bb[4] = {(const float*)d_in[3],  (const float*)d_in[7],
                        (const float*)d_in[11], (const float*)d_in[15]};
  const float* gm[4] = {(const float*)d_in[4],  (const float*)d_in[8],
                        (const float*)d_in[12], (const float*)d_in[16]};
  const float* bt[4] = {(const float*)d_in[5],  (const float*)d_in[9],
                        (const float*)d_in[13], (const float*)d_in[17]};
  const float* Wc = (const float*)d_in[18];
  const float* bc = (const float*)d_in[19];
  (void)in_sizes; (void)n_in; (void)out_size; (void)ws_size;

  // workspace carve (~158 MB; proven-safe envelope)
  char* p = (char*)d_ws;
  auto alloc = [&](size_t bytes)->char*{
    char* r = p; p += (bytes + 255) & ~(size_t)255; return r;
  };
  float* hA     = (float*)alloc((size_t)NN*256*4);   // 51.2 MB, layer activations
  float* hB     = (float*)alloc((size_t)NN*256*4);   // 51.2 MB, pre-BN GEMM acc
  float* aggsC  = (float*)alloc((size_t)NN*256*4);   // 51.2 MB, chunk aggregates
  int*   deg    = (int*)  alloc((size_t)NN*4);
  float* logdeg = (float*)alloc((size_t)NN*4);
  float* amp    = (float*)alloc((size_t)NN*4);
  float* att    = (float*)alloc((size_t)NN*4);
  int*   rowptr = (int*)  alloc((size_t)(NN+1)*4);
  int*   cursor = (int*)  alloc((size_t)NN*4);
  int*   colidx = (int*)  alloc((size_t)NE*4);
  float* colsum = (float*)alloc(256*4);
  float* colss  = (float*)alloc(256*4);
  float* dsum   = (float*)alloc(256);

  hipMemsetAsync(deg, 0, (size_t)NN*4, stream);
  hipMemsetAsync(dsum, 0, 4, stream);

  k_deg     <<<(NE+255)/256, 256, 0, stream>>>(edst, deg);
  k_logdeg  <<<(NN+255)/256, 256, 0, stream>>>(deg, logdeg, dsum);
  k_scalers <<<(NN+255)/256, 256, 0, stream>>>(logdeg, dsum, amp, att);
  k_scan    <<<1, 1024, 0, stream>>>(deg, rowptr, cursor);
  k_fill    <<<(NE+255)/256, 256, 0, stream>>>(esrc, edst, cursor, colidx);
  hipMemcpyAsync(hA, x, (size_t)NN*64*4, hipMemcpyDeviceToDevice, stream);

  const int din[4]  = {64, 128, 256, 128};
  const int dto[4]  = {128, 256, 128, 64};
  for(int l = 0; l < 4; l++){
    int d = din[l], o = dto[l];
    int nch = d / 64;
    dim3 g(o/64, (NN+63)/64);
    for(int c = 0; c < nch; c++){
      int j0 = c*64;
      k_agg_chunk<<<NN, 64, 0, stream>>>(hA, d, j0, rowptr, colidx, aggsC);
      k_gemm_chunk<<<g, 256, 0, stream>>>(hA, d, j0, aggsC, amp, att, W[l], o, bb[l], hB, c==0);
    }
    hipMemsetAsync(colsum, 0, (size_t)o*4, stream);
    hipMemsetAsync(colss,  0, (size_t)o*4, stream);
    k_bn_stats<<<256, 256, 0, stream>>>(hB, o, colsum, colss);
    k_bn_apply<<<(NN*o+255)/256, 256, 0, stream>>>(hB, o, colsum, colss, gm[l], bt[l], hA);
  }
  k_cls<<<(NN*16+255)/256, 256, 0, stream>>>(hA, Wc, bc, (float*)d_out);
}

// Round 5
// 1384.542 us; speedup vs baseline: 1.6667x; 1.6667x over previous
//
#include <hip/hip_runtime.h>
#include <hip/hip_bf16.h>

#define NN 50000
#define NE 800000
#define EPSV 1e-5f

typedef _Float16 h8 __attribute__((ext_vector_type(8)));
typedef float    f4 __attribute__((ext_vector_type(4)));

// ---------------- graph preprocessing ----------------

__global__ void k_deg(const int* __restrict__ dst, int* __restrict__ deg){
  int e = blockIdx.x*blockDim.x + threadIdx.x;
  if(e < NE) atomicAdd(&deg[dst[e]], 1);
}

__global__ void k_logdeg(const int* __restrict__ deg, float* __restrict__ logdeg,
                         float* __restrict__ dsum){
  int i = blockIdx.x*blockDim.x + threadIdx.x;
  float v = 0.f;
  if(i < NN){ v = log1pf((float)deg[i]); logdeg[i] = v; }
  __shared__ float sh[256];
  sh[threadIdx.x] = v; __syncthreads();
  for(int off=128; off>0; off>>=1){
    if(threadIdx.x < off) sh[threadIdx.x] += sh[threadIdx.x+off];
    __syncthreads();
  }
  if(threadIdx.x == 0) atomicAdd(dsum, sh[0]);
}

__global__ void k_scalers(const float* __restrict__ logdeg, const float* __restrict__ dsum,
                          float* __restrict__ amp, float* __restrict__ att){
  int i = blockIdx.x*blockDim.x + threadIdx.x;
  if(i >= NN) return;
  float delta = dsum[0] / (float)NN;
  float ld = logdeg[i];
  amp[i] = ld / delta;
  att[i] = (ld > 0.f) ? (delta / fmaxf(ld, 1e-6f)) : 1.f;
}

__global__ void k_scan(const int* __restrict__ deg, int* __restrict__ rowptr,
                       int* __restrict__ cursor){
  __shared__ int buf[1024];
  __shared__ int s_carry;
  int tid = threadIdx.x;
  if(tid == 0) s_carry = 0;
  __syncthreads();
  for(int base=0; base<NN; base+=1024){
    int i = base + tid;
    int v = (i < NN) ? deg[i] : 0;
    buf[tid] = v; __syncthreads();
    for(int off=1; off<1024; off<<=1){
      int t = (tid >= off) ? buf[tid-off] : 0;
      __syncthreads();
      buf[tid] += t;
      __syncthreads();
    }
    int c = s_carry;
    int excl = c + buf[tid] - v;
    if(i < NN){ rowptr[i] = excl; cursor[i] = excl; }
    __syncthreads();
    if(tid == 1023) s_carry = c + buf[1023];
    __syncthreads();
  }
  if(tid == 0) rowptr[NN] = s_carry;
}

__global__ void k_fill(const int* __restrict__ src, const int* __restrict__ dst,
                       int* __restrict__ cursor, int* __restrict__ colidx){
  int e = blockIdx.x*blockDim.x + threadIdx.x;
  if(e < NE){
    int pos = atomicAdd(&cursor[dst[e]], 1);
    colidx[pos] = src[e];
  }
}

// ---------------- chunked per-node aggregation (fp32) ----------------
// features [j0, j0+64) of h[N,d] -> aggsC[N][4*64] = mean|min|max|std

__global__ void k_agg_chunk(const float* __restrict__ h, int d, int j0,
                            const int* __restrict__ rowptr, const int* __restrict__ colidx,
                            float* __restrict__ aggsC){
  int n = blockIdx.x;
  int j = threadIdx.x;   // 0..63
  int beg = rowptr[n], end = rowptr[n+1];
  float s = 0.f, ss = 0.f, mn = INFINITY, mx = -INFINITY;
  for(int e = beg; e < end; e++){
    int sidx = colidx[e];
    float v = h[(size_t)sidx*d + j0 + j];
    s += v; ss += v*v;
    mn = fminf(mn, v); mx = fmaxf(mx, v);
  }
  float cnt  = (end > beg) ? (float)(end - beg) : 1.f;
  float mean = s / cnt;
  float msq  = ss / cnt;
  float sd   = sqrtf(fmaxf(msq - mean*mean, 0.f) + EPSV);
  if(end <= beg){ mn = 0.f; mx = 0.f; }
  size_t base = (size_t)n * 256;
  aggsC[base + j]       = mean;
  aggsC[base + 64 + j]  = mn;
  aggsC[base + 128 + j] = mx;
  aggsC[base + 192 + j] = sd;
}

// ---------------- W pre-pack: fragment-ready fp16 ----------------
// Wp layout per (layer,chunk): [kb=K/32][nt=o/16][lane=64][j=8] halves,
// with k = kb*32 + (lane>>4)*8 + j, n = nt*16 + (lane&15) and row perm:
//   k<64: j0+k ; k in [64,320): (1+q)d+j0+r ; [320,576): (5+q)d+j0+r ;
//   [576,832): (9+q)d+j0+r   (q=block/64, r=block%64)

__global__ void k_pack(const float* __restrict__ W, int d, int o, int j0,
                       _Float16* __restrict__ Wp){
  int idx = blockIdx.x*256 + threadIdx.x;
  int total = 832*o;
  if(idx >= total) return;
  int j    = idx & 7;
  int lane = (idx >> 3) & 63;
  int rem  = idx >> 9;              // kb*ntiles + nt
  int ntiles = o >> 4;
  int kb = rem / ntiles;
  int nt = rem - kb*ntiles;
  int k = kb*32 + (lane>>4)*8 + j;
  int n = nt*16 + (lane&15);
  int srcrow;
  if(k < 64)       srcrow = j0 + k;
  else if(k < 320){ int t=k-64;  srcrow = (1+(t>>6))*d + j0 + (t&63); }
  else if(k < 576){ int t=k-320; srcrow = (5+(t>>6))*d + j0 + (t&63); }
  else            { int t=k-576; srcrow = (9+(t>>6))*d + j0 + (t&63); }
  Wp[idx] = (_Float16)W[(size_t)srcrow*o + n];
}

// ---------------- MFMA chunked GEMM ----------------
// Per chunk: hB[m,0:o] (+)= virtualA[m,0:832] @ Wp  (+bias on init)
// virtualA = [ hA[m,j0:j0+64] | aggsC[m,:] | amp[m]*aggsC[m,:] | att[m]*aggsC[m,:] ]
// Block: 256 thr = 4 waves; tile 128(M) x 64(N); no LDS, no barriers.
// A frags in-register (fp32 load -> scale -> cvt fp16); B frags direct global.

__global__ __launch_bounds__(256) void k_mfma(
    const float* __restrict__ hA, int d, int j0,
    const float* __restrict__ aggsC,
    const float* __restrict__ amp, const float* __restrict__ att,
    const _Float16* __restrict__ Wp, int o,
    const float* __restrict__ bias,
    float* __restrict__ hB, int init)
{
  int tid  = threadIdx.x;
  int w    = tid >> 6;
  int lane = tid & 63;
  int mi   = lane & 15;      // A-operand row / D col
  int q    = lane >> 4;      // k-quad / D row-quad
  int m0   = blockIdx.y * 128 + w * 32;
  int c0   = blockIdx.x * 64;
  int ntiles = o >> 4;
  int nt0  = blockIdx.x * 4;

  int mrow[2];
  mrow[0] = min(m0 + mi,      NN-1);
  mrow[1] = min(m0 + 16 + mi, NN-1);
  float ampv[2] = { amp[mrow[0]], amp[mrow[1]] };
  float attv[2] = { att[mrow[0]], att[mrow[1]] };
  const float* hAp[2];
  const float* agp[2];
  hAp[0] = hA + (size_t)mrow[0]*d + j0 + q*8;
  hAp[1] = hA + (size_t)mrow[1]*d + j0 + q*8;
  agp[0] = aggsC + (size_t)mrow[0]*256 + q*8;
  agp[1] = aggsC + (size_t)mrow[1]*256 + q*8;

  f4 acc[2][4] = {};

  auto bfrag = [&](int kb, int nn) -> h8 {
    return *(const h8*)(Wp + (((size_t)kb*ntiles + nt0 + nn)*64 + lane)*8);
  };
  auto cvt8 = [](float4 f0, float4 f1, float sc) -> h8 {
    h8 r;
    r[0]=(_Float16)(f0.x*sc); r[1]=(_Float16)(f0.y*sc);
    r[2]=(_Float16)(f0.z*sc); r[3]=(_Float16)(f0.w*sc);
    r[4]=(_Float16)(f1.x*sc); r[5]=(_Float16)(f1.y*sc);
    r[6]=(_Float16)(f1.z*sc); r[7]=(_Float16)(f1.w*sc);
    return r;
  };

  // ---- phase X: hA chunk, kb = 0,1 ----
  #pragma unroll
  for(int kb = 0; kb < 2; kb++){
    h8 a[2];
    #pragma unroll
    for(int t = 0; t < 2; t++){
      float4 f0 = *(const float4*)(hAp[t] + kb*32);
      float4 f1 = *(const float4*)(hAp[t] + kb*32 + 4);
      a[t] = cvt8(f0, f1, 1.f);
    }
    #pragma unroll
    for(int t = 0; t < 2; t++)
      #pragma unroll
      for(int nn = 0; nn < 4; nn++)
        acc[t][nn] = __builtin_amdgcn_mfma_f32_16x16x32_f16(a[t], bfrag(kb,nn), acc[t][nn], 0,0,0);
  }

  // ---- aggs phases: load aggs once, 3 scale variants, kb = 2+kb2 / 10+kb2 / 18+kb2 ----
  #pragma unroll 2
  for(int kb2 = 0; kb2 < 8; kb2++){
    h8 apl[2], aam[2], aat[2];
    #pragma unroll
    for(int t = 0; t < 2; t++){
      float4 f0 = *(const float4*)(agp[t] + kb2*32);
      float4 f1 = *(const float4*)(agp[t] + kb2*32 + 4);
      apl[t] = cvt8(f0, f1, 1.f);
      aam[t] = cvt8(f0, f1, ampv[t]);
      aat[t] = cvt8(f0, f1, attv[t]);
    }
    #pragma unroll
    for(int t = 0; t < 2; t++){
      #pragma unroll
      for(int nn = 0; nn < 4; nn++){
        acc[t][nn] = __builtin_amdgcn_mfma_f32_16x16x32_f16(apl[t], bfrag(2+kb2,  nn), acc[t][nn], 0,0,0);
        acc[t][nn] = __builtin_amdgcn_mfma_f32_16x16x32_f16(aam[t], bfrag(10+kb2, nn), acc[t][nn], 0,0,0);
        acc[t][nn] = __builtin_amdgcn_mfma_f32_16x16x32_f16(aat[t], bfrag(18+kb2, nn), acc[t][nn], 0,0,0);
      }
    }
  }

  // ---- epilogue: D col = lane&15, row = q*4 + reg ----
  #pragma unroll
  for(int t = 0; t < 2; t++){
    #pragma unroll
    for(int nn = 0; nn < 4; nn++){
      int n = c0 + nn*16 + mi;
      #pragma unroll
      for(int r = 0; r < 4; r++){
        int m = m0 + t*16 + q*4 + r;
        if(m < NN){
          float* cp = hB + (size_t)m*o + n;
          float base = init ? bias[n] : *cp;
          *cp = base + acc[t][nn][r];
        }
      }
    }
  }
}

// ---------------- ReLU + BatchNorm (fp32) ----------------

__global__ __launch_bounds__(256) void k_bn_stats(const float* __restrict__ H, int dout,
                                                  float* __restrict__ colsum, float* __restrict__ colss){
  int tid = threadIdx.x;
  int gid = blockIdx.x*256 + tid;
  int stride = gridDim.x*256;
  int total = NN * dout;
  float s = 0.f, ss = 0.f;
  for(int i = gid; i < total; i += stride){
    float v = fmaxf(H[i], 0.f);
    s += v; ss += v*v;
  }
  __shared__ float shs[256], shss[256];
  shs[tid] = s; shss[tid] = ss;
  __syncthreads();
  if(tid < dout){
    float ts = 0.f, tss = 0.f;
    for(int i = tid; i < 256; i += dout){ ts += shs[i]; tss += shss[i]; }
    atomicAdd(&colsum[tid], ts);
    atomicAdd(&colss[tid], tss);
  }
}

__global__ void k_bn_apply(const float* __restrict__ H, int dout,
                           const float* __restrict__ colsum, const float* __restrict__ colss,
                           const float* __restrict__ gamma, const float* __restrict__ beta,
                           float* __restrict__ out){
  int i = blockIdx.x*blockDim.x + threadIdx.x;
  int total = NN * dout;
  if(i >= total) return;
  int c = i & (dout - 1);
  float mean = colsum[c] / (float)NN;
  float var  = colss[c] / (float)NN - mean*mean;
  float inv  = rsqrtf(fmaxf(var, 0.f) + EPSV);
  float v = fmaxf(H[i], 0.f);
  out[i] = (v - mean) * inv * gamma[c] + beta[c];
}

// ---------------- classifier (fp32) ----------------

__global__ __launch_bounds__(256) void k_cls(const float* __restrict__ h,
    const float* __restrict__ Wc, const float* __restrict__ bc,
    float* __restrict__ out){
  __shared__ float w[640];
  __shared__ float bb[16];
  int tid = threadIdx.x;
  for(int i = tid; i < 640; i += 256) w[i] = Wc[i];
  if(tid < 10) bb[tid] = bc[tid];
  __syncthreads();
  int idx = blockIdx.x*256 + tid;
  int n = idx >> 4;
  int c = idx & 15;
  if(n < NN && c < 10){
    float acc = bb[c];
    const float* hp = h + (size_t)n*64;
    #pragma unroll
    for(int k = 0; k < 64; k++) acc += hp[k] * w[k*10 + c];
    out[(size_t)n*10 + c] = acc;
  }
}

// ---------------- launch ----------------

extern "C" void kernel_launch(void* const* d_in, const int* in_sizes, int n_in,
                              void* d_out, int out_size, void* d_ws, size_t ws_size,
                              hipStream_t stream){
  const float* x = (const float*)d_in[0];
  const int* edge = (const int*)d_in[1];
  const int* esrc = edge;
  const int* edst = edge + NE;
  const float* W[4]  = {(const float*)d_in[2],  (const float*)d_in[6],
                        (const float*)d_in[10], (const float*)d_in[14]};
  const float* bb[4] = {(const float*)d_in[3],  (const float*)d_in[7],
                        (const float*)d_in[11], (const float*)d_in[15]};
  const float* gm[4] = {(const float*)d_in[4],  (const float*)d_in[8],
                        (const float*)d_in[12], (const float*)d_in[16]};
  const float* bt[4] = {(const float*)d_in[5],  (const float*)d_in[9],
                        (const float*)d_in[13], (const float*)d_in[17]};
  const float* Wc = (const float*)d_in[18];
  const float* bc = (const float*)d_in[19];
  (void)in_sizes; (void)n_in; (void)out_size; (void)ws_size;

  // workspace carve (~160 MB; proven-safe envelope)
  char* p = (char*)d_ws;
  auto alloc = [&](size_t bytes)->char*{
    char* r = p; p += (bytes + 255) & ~(size_t)255; return r;
  };
  float* hA     = (float*)alloc((size_t)NN*256*4);   // 51.2 MB
  float* hB     = (float*)alloc((size_t)NN*256*4);   // 51.2 MB
  float* aggsC  = (float*)alloc((size_t)NN*256*4);   // 51.2 MB
  int*   deg    = (int*)  alloc((size_t)NN*4);
  float* logdeg = (float*)alloc((size_t)NN*4);
  float* amp    = (float*)alloc((size_t)NN*4);
  float* att    = (float*)alloc((size_t)NN*4);
  int*   rowptr = (int*)  alloc((size_t)(NN+1)*4);
  int*   cursor = (int*)  alloc((size_t)NN*4);
  int*   colidx = (int*)  alloc((size_t)NE*4);
  float* colsum = (float*)alloc(256*4);
  float* colss  = (float*)alloc(256*4);
  float* dsum   = (float*)alloc(256);

  // packed fp16 weights per (layer,chunk): 832*o halves each (~2.1 MB total)
  const int din[4]  = {64, 128, 256, 128};
  const int dto[4]  = {128, 256, 128, 64};
  _Float16* Wp[4][4];
  for(int l = 0; l < 4; l++)
    for(int c = 0; c < din[l]/64; c++)
      Wp[l][c] = (_Float16*)alloc((size_t)832*dto[l]*2);

  // pack all weights up front
  for(int l = 0; l < 4; l++)
    for(int c = 0; c < din[l]/64; c++)
      k_pack<<<(832*dto[l]+255)/256, 256, 0, stream>>>(W[l], din[l], dto[l], c*64, Wp[l][c]);

  hipMemsetAsync(deg, 0, (size_t)NN*4, stream);
  hipMemsetAsync(dsum, 0, 4, stream);

  k_deg     <<<(NE+255)/256, 256, 0, stream>>>(edst, deg);
  k_logdeg  <<<(NN+255)/256, 256, 0, stream>>>(deg, logdeg, dsum);
  k_scalers <<<(NN+255)/256, 256, 0, stream>>>(logdeg, dsum, amp, att);
  k_scan    <<<1, 1024, 0, stream>>>(deg, rowptr, cursor);
  k_fill    <<<(NE+255)/256, 256, 0, stream>>>(esrc, edst, cursor, colidx);
  hipMemcpyAsync(hA, x, (size_t)NN*64*4, hipMemcpyDeviceToDevice, stream);

  for(int l = 0; l < 4; l++){
    int d = din[l], o = dto[l];
    int nch = d / 64;
    dim3 g(o/64, (NN+127)/128);
    for(int c = 0; c < nch; c++){
      int j0 = c*64;
      k_agg_chunk<<<NN, 64, 0, stream>>>(hA, d, j0, rowptr, colidx, aggsC);
      k_mfma<<<g, 256, 0, stream>>>(hA, d, j0, aggsC, amp, att, Wp[l][c], o, bb[l], hB, c==0);
    }
    hipMemsetAsync(colsum, 0, (size_t)o*4, stream);
    hipMemsetAsync(colss,  0, (size_t)o*4, stream);
    k_bn_stats<<<256, 256, 0, stream>>>(hB, o, colsum, colss);
    k_bn_apply<<<(NN*o+255)/256, 256, 0, stream>>>(hB, o, colsum, colss, gm[l], bt[l], hA);
  }
  k_cls<<<(NN*16+255)/256, 256, 0, stream>>>(hA, Wc, bc, (float*)d_out);
}